// Round 10
// baseline (921.644 us; speedup 1.0000x reference)
//
#include <hip/hip_runtime.h>
#include <hip/hip_cooperative_groups.h>

namespace cg = cooperative_groups;

typedef unsigned short u16;
typedef unsigned int u32;
typedef __attribute__((ext_vector_type(4))) u16 u16x4;
typedef __attribute__((ext_vector_type(8))) u16 u16x8;
typedef __attribute__((ext_vector_type(4))) u32 u32x4;
typedef __attribute__((ext_vector_type(8))) short short8;   // MFMA A/B frag (8 bf16)
typedef __attribute__((ext_vector_type(4))) float f32x4;    // MFMA C/D frag
typedef __attribute__((ext_vector_type(4))) float f4;
typedef __attribute__((ext_vector_type(2))) float f2;

#define NN 50000
#define NE 600000
#define HEADS 4
#define DH 32
#define HIDU 128
#define NC 10
#define NBLK 196    // ceil(NN/256)
#define PREPB_CAP 1792
#define WES_T 34    // WeS t-stride (bank-spread)
#define WES_H 546   // WeS h-stride = 16*34 + 2

// logit scale folded with log2(e): (1/sqrt(32)) * 1.4426950408889634
#define SCALE2 0.25503486164f

__device__ __forceinline__ float bf2f(u16 u) {
    union { unsigned int i; float f; } c; c.i = ((unsigned int)u) << 16; return c.f;
}
__device__ __forceinline__ u16 f2bf(float f) {
    union { float f; unsigned int i; } c; c.f = f;
    unsigned int x = c.i;
    return (u16)((x + 0x7fffu + ((x >> 16) & 1u)) >> 16);  // RNE
}
__device__ __forceinline__ float lo_bf(u32 d) { return __uint_as_float(d << 16); }
__device__ __forceinline__ float hi_bf(u32 d) { return __uint_as_float(d & 0xffff0000u); }
// quad butterflies via DPP (VALU-only)
__device__ __forceinline__ float qadd_xor1(float v) {
    int o = __builtin_amdgcn_update_dpp(0, __float_as_int(v), 0xB1, 0xF, 0xF, true);
    return v + __int_as_float(o);
}
__device__ __forceinline__ float qadd_xor2(float v) {
    int o = __builtin_amdgcn_update_dpp(0, __float_as_int(v), 0x4E, 0xF, 0xF, true);
    return v + __int_as_float(o);
}

// ---------------- fused preprocessing (cooperative, 1 dispatch, grid-size-agnostic) ----
// phase 0: zero deg + weight cvt/transpose | 1: degree hist | 2: per-chunk block sums |
// 3: scan bsum (block 0) | 4: per-chunk scan -> row_ptr/cursor | 5: scatter csr + ea16
__global__ __launch_bounds__(256) void k_prep(
    const int* __restrict__ ei, const float* __restrict__ eattr,
    const float* w0, const float* w1, const float* w2, const float* w3,
    const float* w4, const float* w5, const float* w6, const float* w7,
    int* __restrict__ deg, int* __restrict__ bsum, int* __restrict__ boff,
    int* __restrict__ row_ptr, int* __restrict__ cursor,
    int* __restrict__ csr_src, u16* __restrict__ ea16, u16* __restrict__ wthi)
{
    cg::grid_group grid = cg::this_grid();
    __shared__ int s[256];
    __shared__ int red[4];
    const int t = threadIdx.x;
    const int gid = blockIdx.x * 256 + t;
    const int gsz = gridDim.x * 256;

    // phase 0: zero deg + cvtw (independent, grid-stride)
    for (int i = gid; i < NN; i += gsz) deg[i] = 0;
    for (int idx = gid; idx < 8 * 16384; idx += gsz) {
        int mat = idx >> 14;
        int r   = idx & 16383;          // k*128 + n
        int k = r >> 7, n = r & 127;
        const float* w;
        switch (mat) {
            case 0: w = w0; break; case 1: w = w1; break;
            case 2: w = w2; break; case 3: w = w3; break;
            case 4: w = w4; break; case 5: w = w5; break;
            case 6: w = w6; break; default: w = w7; break;
        }
        wthi[mat * 16384 + n * 128 + k] = f2bf(w[r]);
    }
    grid.sync();

    // phase 1: degree histogram (grid-stride)
    for (int e = gid; e < NE; e += gsz) atomicAdd(&deg[ei[NE + e]], 1);
    grid.sync();

    // phase 2: per-chunk degree sums (chunk c covers nodes c*256..c*256+255)
    for (int c = blockIdx.x; c < NBLK; c += gridDim.x) {
        int i = c * 256 + t;
        int v = (i < NN) ? deg[i] : 0;
        #pragma unroll
        for (int off = 1; off < 64; off <<= 1) v += __shfl_xor(v, off);
        if ((t & 63) == 0) red[t >> 6] = v;
        __syncthreads();
        if (t == 0) bsum[c] = red[0] + red[1] + red[2] + red[3];
        __syncthreads();
    }
    grid.sync();

    // phase 3: block 0 scans bsum -> boff (exclusive)
    if (blockIdx.x == 0) {
        int v = (t < NBLK) ? bsum[t] : 0;
        s[t] = v;
        __syncthreads();
        for (int off = 1; off < 256; off <<= 1) {
            int x = (t >= off) ? s[t - off] : 0;
            __syncthreads();
            s[t] += x;
            __syncthreads();
        }
        if (t < NBLK) boff[t] = s[t] - v;
        if (t == 0) row_ptr[NN] = NE;
    }
    grid.sync();

    // phase 4: per-chunk exclusive scan -> row_ptr, cursor
    for (int c = blockIdx.x; c < NBLK; c += gridDim.x) {
        int i = c * 256 + t;
        int v = (i < NN) ? deg[i] : 0;
        s[t] = v;
        __syncthreads();
        for (int off = 1; off < 256; off <<= 1) {
            int x = (t >= off) ? s[t - off] : 0;
            __syncthreads();
            s[t] += x;
            __syncthreads();
        }
        if (i < NN) {
            int r = boff[c] + s[t] - v;
            row_ptr[i] = r;
            cursor[i] = r;
        }
        __syncthreads();
    }
    grid.sync();

    // phase 5: scatter csr_src + permute edge_attr into CSR order (fp32 -> bf16)
    for (int i = gid; i < NE; i += gsz) {
        int sN = ei[i];
        int d  = ei[NE + i];
        int pos = atomicAdd(&cursor[d], 1);
        csr_src[pos] = sN;
        const f4* ep = (const f4*)(eattr + (size_t)i * 16);
        f4 a = ep[0], b = ep[1], c2 = ep[2], dd = ep[3];
        u16x8 o0, o1;
        #pragma unroll
        for (int j = 0; j < 4; j++) {
            o0[j] = f2bf(a[j]); o0[4 + j] = f2bf(b[j]);
            o1[j] = f2bf(c2[j]); o1[4 + j] = f2bf(dd[j]);
        }
        *(u16x8*)(ea16 + (size_t)pos * 16)     = o0;
        *(u16x8*)(ea16 + (size_t)pos * 16 + 8) = o1;
    }
}

// ---------------- fallback preprocessing (ordinary kernels, R7-proven) ----------------
__global__ void k_zcvt(const float* w0, const float* w1, const float* w2, const float* w3,
                       const float* w4, const float* w5, const float* w6, const float* w7,
                       int* __restrict__ deg, u16* __restrict__ wthi) {
    int gid = blockIdx.x * 256 + threadIdx.x;
    int gsz = gridDim.x * 256;
    for (int i = gid; i < NN; i += gsz) deg[i] = 0;
    for (int idx = gid; idx < 8 * 16384; idx += gsz) {
        int mat = idx >> 14;
        int r   = idx & 16383;
        int k = r >> 7, n = r & 127;
        const float* w;
        switch (mat) {
            case 0: w = w0; break; case 1: w = w1; break;
            case 2: w = w2; break; case 3: w = w3; break;
            case 4: w = w4; break; case 5: w = w5; break;
            case 6: w = w6; break; default: w = w7; break;
        }
        wthi[mat * 16384 + n * 128 + k] = f2bf(w[r]);
    }
}

__global__ void k_hist(const int* __restrict__ dst, int* __restrict__ deg) {
    int i = blockIdx.x * blockDim.x + threadIdx.x;
    if (i < NE) atomicAdd(&deg[dst[i]], 1);
}

__global__ __launch_bounds__(256) void scan_a(const int* __restrict__ deg,
                                              int* __restrict__ bsum) {
    __shared__ int red[4];
    int i = blockIdx.x * 256 + threadIdx.x;
    int v = (i < NN) ? deg[i] : 0;
    #pragma unroll
    for (int off = 1; off < 64; off <<= 1) v += __shfl_xor(v, off);
    if ((threadIdx.x & 63) == 0) red[threadIdx.x >> 6] = v;
    __syncthreads();
    if (threadIdx.x == 0) bsum[blockIdx.x] = red[0] + red[1] + red[2] + red[3];
}

__global__ __launch_bounds__(256) void scan_b(const int* __restrict__ bsum,
                                              int* __restrict__ boff,
                                              int* __restrict__ row_ptr) {
    __shared__ int s[256];
    int t = threadIdx.x;
    int v = (t < NBLK) ? bsum[t] : 0;
    s[t] = v;
    __syncthreads();
    for (int off = 1; off < 256; off <<= 1) {
        int x = (t >= off) ? s[t - off] : 0;
        __syncthreads();
        s[t] += x;
        __syncthreads();
    }
    if (t < NBLK) boff[t] = s[t] - v;   // exclusive
    if (t == 0) row_ptr[NN] = NE;
}

__global__ __launch_bounds__(256) void scan_c(const int* __restrict__ deg,
                                              const int* __restrict__ boff,
                                              int* __restrict__ row_ptr,
                                              int* __restrict__ cursor) {
    __shared__ int s[256];
    int t = threadIdx.x;
    int i = blockIdx.x * 256 + t;
    int v = (i < NN) ? deg[i] : 0;
    s[t] = v;
    __syncthreads();
    for (int off = 1; off < 256; off <<= 1) {
        int x = (t >= off) ? s[t - off] : 0;
        __syncthreads();
        s[t] += x;
        __syncthreads();
    }
    if (i < NN) {
        int r = boff[blockIdx.x] + s[t] - v;
        row_ptr[i] = r;
        cursor[i] = r;
    }
}

__global__ void k_scatter(const int* __restrict__ ei, const float* __restrict__ eattr,
                          int* __restrict__ cursor,
                          int* __restrict__ csr_src, u16* __restrict__ ea16) {
    int i = blockIdx.x * blockDim.x + threadIdx.x;
    if (i < NE) {
        int sN = ei[i];
        int d = ei[NE + i];
        int pos = atomicAdd(&cursor[d], 1);
        csr_src[pos] = sN;
        const f4* ep = (const f4*)(eattr + (size_t)i * 16);
        f4 a = ep[0], b = ep[1], c = ep[2], dd = ep[3];
        u16x8 o0, o1;
        #pragma unroll
        for (int j = 0; j < 4; j++) {
            o0[j] = f2bf(a[j]); o0[4 + j] = f2bf(b[j]);
            o1[j] = f2bf(c[j]); o1[4 + j] = f2bf(dd[j]);
        }
        *(u16x8*)(ea16 + (size_t)pos * 16)     = o0;
        *(u16x8*)(ea16 + (size_t)pos * 16 + 8) = o1;
    }
}

// ---------------- unified q/k/v/s GEMM: 4 mats per block, X read ONCE -----------
// grid (391). A-fragments (K=128) live in registers; loop mats {reload Bs, MFMA, write}.
// q,s -> fp32; k,v -> bf16. XB=0: X fp32 (trunc); XB=1: X bf16.
template<int XB>
__global__ __launch_bounds__(256) void gemm4(
    const void* __restrict__ Xv, const u16* __restrict__ WtHi,
    const float* __restrict__ b0, const float* __restrict__ b1,
    const float* __restrict__ b2, const float* __restrict__ b3,
    float* __restrict__ outq, u16* __restrict__ outk, u16* __restrict__ outv,
    float* __restrict__ outs, int nrows)
{
    __shared__ u16 Bs[128 * 128];   // 32 KB
    const float* Xf = (const float*)Xv;
    const u16*   Xh = (const u16*)Xv;

    const int wave = threadIdx.x >> 6, lane = threadIdx.x & 63;
    const int n0 = lane & 15;
    const int qw = lane >> 4;
    const int kq = qw * 8;

    // ---- load A-fragments ONCE (per lane: 2 row-tiles x 4 k-slices x 8 bf16 = 32 VGPR)
    short8 ah[2][4];
    #pragma unroll
    for (int rt = 0; rt < 2; rt++) {
        int arow = blockIdx.x * 128 + wave * 32 + rt * 16 + n0;
        int arow_c = arow < nrows ? arow : nrows - 1;
        size_t xbase = (size_t)arow_c * HIDU + kq;
        #pragma unroll
        for (int ks = 0; ks < 4; ks++) {
            if (XB) {
                ah[rt][ks] = *(const short8*)(Xh + xbase + ks * 32);
            } else {
                f4 a0 = *(const f4*)(Xf + xbase + ks * 32);
                f4 a1 = *(const f4*)(Xf + xbase + ks * 32 + 4);
                #pragma unroll
                for (int j = 0; j < 4; j++) {
                    ah[rt][ks][j]     = (short)(__float_as_uint(a0[j]) >> 16);
                    ah[rt][ks][4 + j] = (short)(__float_as_uint(a1[j]) >> 16);
                }
            }
        }
    }

    #pragma unroll
    for (int mat = 0; mat < 4; mat++) {
        if (mat > 0) __syncthreads();   // all waves done reading previous Bs
        const u16* wh = WtHi + mat * 16384;
        #pragma unroll
        for (int i = 0; i < 8; i++) {
            int idx = threadIdx.x + i * 256;
            int n = idx >> 4, g = idx & 15;
            *(u16x8*)(&Bs[n * 128 + ((g ^ (n & 15)) << 3)]) = *(const u16x8*)(wh + n * 128 + g * 8);
        }
        __syncthreads();

        f32x4 acc[2][8];
        #pragma unroll
        for (int rt = 0; rt < 2; rt++)
            #pragma unroll
            for (int nt = 0; nt < 8; nt++) acc[rt][nt] = (f32x4){0.f, 0.f, 0.f, 0.f};

        #pragma unroll
        for (int ks = 0; ks < 4; ks++) {
            #pragma unroll
            for (int nt = 0; nt < 8; nt++) {
                const int boff = (nt * 16 + n0) * 128 + (((ks << 2) + qw) ^ n0) * 8;
                short8 bh = *(const short8*)(&Bs[boff]);
                #pragma unroll
                for (int rt = 0; rt < 2; rt++)
                    acc[rt][nt] = __builtin_amdgcn_mfma_f32_16x16x32_bf16(ah[rt][ks], bh, acc[rt][nt], 0, 0, 0);
            }
        }

        const float* bia = (mat == 0) ? b0 : (mat == 1) ? b1 : (mat == 2) ? b2 : b3;
        #pragma unroll
        for (int rt = 0; rt < 2; rt++) {
            const int rbase = blockIdx.x * 128 + wave * 32 + rt * 16 + qw * 4;
            #pragma unroll
            for (int nt = 0; nt < 8; nt++) {
                int col = nt * 16 + n0;
                float bv = bia[col];
                #pragma unroll
                for (int r = 0; r < 4; r++) {
                    int grow = rbase + r;
                    if (grow < nrows) {
                        float v = acc[rt][nt][r] + bv;
                        if (mat == 0)      outq[(size_t)grow * HIDU + col] = v;
                        else if (mat == 1) outk[(size_t)grow * HIDU + col] = f2bf(v);
                        else if (mat == 2) outv[(size_t)grow * HIDU + col] = f2bf(v);
                        else               outs[(size_t)grow * HIDU + col] = v;
                    }
                }
            }
        }
    }
}

// ---------------- fused attention (+ optional fused head) ----------------
// 16 lanes per node (4 heads x 4 subs); DPP quad butterflies; f4 packed math.
// Max-free single-pass softmax (verified R2-R8). 32-bit gather offsets.
// MODE 0: write relu(conv_out) rows bf16. MODE 1: fused output head + log_softmax.
template<int MODE>
__global__ __launch_bounds__(256) void attn_t(
    const float* __restrict__ qb, const u16* __restrict__ kb, const u16* __restrict__ vb,
    const float* __restrict__ sb, const u16* __restrict__ ea16, const float* __restrict__ We,
    const int* __restrict__ row_ptr, const int* __restrict__ csr_src,
    u16* __restrict__ hout_b16,
    const float* __restrict__ Wout, const float* __restrict__ bout,
    float* __restrict__ out_logits)
{
    __shared__ float WeS[4 * WES_H];    // ~8.7 KB
    __shared__ float WoT[MODE ? (NC * HIDU) : 1];  // transposed head weights (mode 1)
    __shared__ float boS[MODE ? NC : 1];

    #pragma unroll
    for (int i = 0; i < 8; i++) {
        int idx = threadIdx.x + i * 256;   // t*128 + c over 16x128
        int tt = idx >> 7, c = idx & 127;
        int h = c >> 5, j = c & 31;
        WeS[h * WES_H + tt * WES_T + j] = We[idx];
    }
    if (MODE == 1) {
        #pragma unroll
        for (int i = 0; i < 5; i++) {
            int idx = threadIdx.x + i * 256;
            if (idx < HIDU * NC) {
                int c = idx >> 7, ch = idx & 127;       // WoT[c][ch] = Wout[ch][c]
                WoT[idx] = Wout[ch * NC + c];
            }
        }
        if (threadIdx.x < NC) boS[threadIdx.x] = bout[threadIdx.x];
    }
    __syncthreads();

    int gtid = blockIdx.x * 256 + threadIdx.x;   // grid is exactly NN*16 threads
    int n   = gtid >> 4;
    int l16 = gtid & 15;
    int h   = l16 >> 2;
    int sub = l16 & 3;
    const int lane = threadIdx.x & 63;
    const float* WeH = &WeS[h * WES_H];
    const int j0  = sub * 8;
    const int ch0 = h * DH + j0;   // = l16*8
    const int t0  = sub * 4;

    // own 8 q channels (coalesced: 16 lanes cover the full 128-f32 row)
    f4 qa, qbv;
    {
        const f4* qp = (const f4*)(qb + (size_t)n * HIDU + ch0);
        qa = qp[0]; qbv = qp[1];
    }

    // g[t] = q_head . We[t, head]: partial over own 8 channels for all 16 t,
    // then quad butterfly-reduce across the 4 sub-lanes.
    f4 g4v;
    {
        float part[16];
        #pragma unroll
        for (int t = 0; t < 16; t++) {
            const f2* wp = (const f2*)(WeH + t * WES_T + j0);
            f2 w0 = wp[0], w1 = wp[1], w2 = wp[2], w3 = wp[3];
            part[t] = qa[0] * w0.x + qa[1] * w0.y + qa[2] * w1.x + qa[3] * w1.y
                    + qbv[0] * w2.x + qbv[1] * w2.y + qbv[2] * w3.x + qbv[3] * w3.y;
        }
        #pragma unroll
        for (int t = 0; t < 16; t++) { part[t] = qadd_xor1(part[t]); part[t] = qadd_xor2(part[t]); }
        g4v[0] = part[t0]; g4v[1] = part[t0 + 1]; g4v[2] = part[t0 + 2]; g4v[3] = part[t0 + 3];
    }

    float l = 0.f;
    f4 O0 = {0.f, 0.f, 0.f, 0.f}, O1 = {0.f, 0.f, 0.f, 0.f};
    f4 a4 = {0.f, 0.f, 0.f, 0.f};

    const int r0 = row_ptr[n], r1 = row_ptr[n + 1];

    for (int e = r0; e < r1; e += 4) {
        const int e1 = (e + 1 < r1) ? e + 1 : e;
        const int e2 = (e + 2 < r1) ? e + 2 : e;
        const int e3 = (e + 3 < r1) ? e + 3 : e;
        // issue ALL loads up-front (MLP); all offsets 32-bit (buffers < 20 MB)
        int s0 = csr_src[e], s1 = csr_src[e1], s2 = csr_src[e2], s3 = csr_src[e3];
        u32 eo0 = (u32)e  * 16u + t0, eo1 = (u32)e1 * 16u + t0;
        u32 eo2 = (u32)e2 * 16u + t0, eo3 = (u32)e3 * 16u + t0;
        u16x4 x0 = *(const u16x4*)(ea16 + eo0);
        u16x4 x1 = *(const u16x4*)(ea16 + eo1);
        u16x4 x2 = *(const u16x4*)(ea16 + eo2);
        u16x4 x3 = *(const u16x4*)(ea16 + eo3);
        u32 ko0 = (u32)s0 * 128u + ch0, ko1 = (u32)s1 * 128u + ch0;
        u32 ko2 = (u32)s2 * 128u + ch0, ko3 = (u32)s3 * 128u + ch0;
        u32x4 k0 = *(const u32x4*)(kb + ko0);
        u32x4 k1 = *(const u32x4*)(kb + ko1);
        u32x4 k2 = *(const u32x4*)(kb + ko2);
        u32x4 k3 = *(const u32x4*)(kb + ko3);
        u32x4 v0 = *(const u32x4*)(vb + ko0);
        u32x4 v1 = *(const u32x4*)(vb + ko1);
        u32x4 v2 = *(const u32x4*)(vb + ko2);
        u32x4 v3 = *(const u32x4*)(vb + ko3);

        f4 ea0 = {bf2f(x0[0]), bf2f(x0[1]), bf2f(x0[2]), bf2f(x0[3])};
        f4 ea1 = {bf2f(x1[0]), bf2f(x1[1]), bf2f(x1[2]), bf2f(x1[3])};
        f4 ea2 = {bf2f(x2[0]), bf2f(x2[1]), bf2f(x2[2]), bf2f(x2[3])};
        f4 ea3 = {bf2f(x3[0]), bf2f(x3[1]), bf2f(x3[2]), bf2f(x3[3])};

        f4 ac0 = qa * (f4){lo_bf(k0[0]), hi_bf(k0[0]), lo_bf(k0[1]), hi_bf(k0[1])}
               + qbv * (f4){lo_bf(k0[2]), hi_bf(k0[2]), lo_bf(k0[3]), hi_bf(k0[3])}
               + g4v * ea0;
        f4 ac1 = qa * (f4){lo_bf(k1[0]), hi_bf(k1[0]), lo_bf(k1[1]), hi_bf(k1[1])}
               + qbv * (f4){lo_bf(k1[2]), hi_bf(k1[2]), lo_bf(k1[3]), hi_bf(k1[3])}
               + g4v * ea1;
        f4 ac2 = qa * (f4){lo_bf(k2[0]), hi_bf(k2[0]), lo_bf(k2[1]), hi_bf(k2[1])}
               + qbv * (f4){lo_bf(k2[2]), hi_bf(k2[2]), lo_bf(k2[3]), hi_bf(k2[3])}
               + g4v * ea2;
        f4 ac3 = qa * (f4){lo_bf(k3[0]), hi_bf(k3[0]), lo_bf(k3[1]), hi_bf(k3[1])}
               + qbv * (f4){lo_bf(k3[2]), hi_bf(k3[2]), lo_bf(k3[3]), hi_bf(k3[3])}
               + g4v * ea3;
        float d0 = (ac0[0] + ac0[1]) + (ac0[2] + ac0[3]);
        float d1 = (ac1[0] + ac1[1]) + (ac1[2] + ac1[3]);
        float d2 = (ac2[0] + ac2[1]) + (ac2[2] + ac2[3]);
        float d3 = (ac3[0] + ac3[1]) + (ac3[2] + ac3[3]);
        d0 = qadd_xor1(d0); d1 = qadd_xor1(d1); d2 = qadd_xor1(d2); d3 = qadd_xor1(d3);
        d0 = qadd_xor2(d0); d1 = qadd_xor2(d1); d2 = qadd_xor2(d2); d3 = qadd_xor2(d3);

        // max-free softmax weights (logits provably small for this model; verified R2-R8)
        float w0 = exp2f(d0 * SCALE2);
        float w1 = (e + 1 < r1) ? exp2f(d1 * SCALE2) : 0.f;
        float w2 = (e + 2 < r1) ? exp2f(d2 * SCALE2) : 0.f;
        float w3 = (e + 3 < r1) ? exp2f(d3 * SCALE2) : 0.f;
        l += (w0 + w1) + (w2 + w3);

        O0 = O0
           + (f4){lo_bf(v0[0]), hi_bf(v0[0]), lo_bf(v0[1]), hi_bf(v0[1])} * w0
           + (f4){lo_bf(v1[0]), hi_bf(v1[0]), lo_bf(v1[1]), hi_bf(v1[1])} * w1
           + (f4){lo_bf(v2[0]), hi_bf(v2[0]), lo_bf(v2[1]), hi_bf(v2[1])} * w2
           + (f4){lo_bf(v3[0]), hi_bf(v3[0]), lo_bf(v3[1]), hi_bf(v3[1])} * w3;
        O1 = O1
           + (f4){lo_bf(v0[2]), hi_bf(v0[2]), lo_bf(v0[3]), hi_bf(v0[3])} * w0
           + (f4){lo_bf(v1[2]), hi_bf(v1[2]), lo_bf(v1[3]), hi_bf(v1[3])} * w1
           + (f4){lo_bf(v2[2]), hi_bf(v2[2]), lo_bf(v2[3]), hi_bf(v2[3])} * w2
           + (f4){lo_bf(v3[2]), hi_bf(v3[2]), lo_bf(v3[3]), hi_bf(v3[3])} * w3;
        a4 = a4 + ea0 * w0 + ea1 * w1 + ea2 * w2 + ea3 * w3;
    }

    // gather distributed a16 (from the 4 lanes of this head)
    float af[16];
    #pragma unroll
    for (int t = 0; t < 16; t++)
        af[t] = __shfl(a4[t & 3], (lane & ~3) | (t >> 2));

    float invl = 1.0f / (l + 1e-16f);     // PyG softmax eps; zero-degree -> O=0
    const f4* sp = (const f4*)(sb + (size_t)n * HIDU + ch0);
    f4 sp0 = sp[0], sp1 = sp[1];

    // ev_j = sum_t af[t] * WeH[t][j0+j]  (vectorized b64 LDS reads)
    f4 evA = {0.f, 0.f, 0.f, 0.f}, evB = {0.f, 0.f, 0.f, 0.f};
    #pragma unroll
    for (int t = 0; t < 16; t++) {
        float a = af[t];
        const f2* wp = (const f2*)(WeH + t * WES_T + j0);
        f2 w0 = wp[0], w1 = wp[1], w2 = wp[2], w3 = wp[3];
        evA[0] += a * w0.x; evA[1] += a * w0.y; evA[2] += a * w1.x; evA[3] += a * w1.y;
        evB[0] += a * w2.x; evB[1] += a * w2.y; evB[2] += a * w3.x; evB[3] += a * w3.y;
    }

    f4 val0, val1;
    #pragma unroll
    for (int j = 0; j < 4; j++) {
        val0[j] = fmaxf((O0[j] + evA[j]) * invl + sp0[j], 0.f);
        val1[j] = fmaxf((O1[j] + evB[j]) * invl + sp1[j], 0.f);
    }

    if (MODE == 0) {
        u16x8 hv;
        #pragma unroll
        for (int j = 0; j < 4; j++) { hv[j] = f2bf(val0[j]); hv[4 + j] = f2bf(val1[j]); }
        *(u16x8*)(hout_b16 + (u32)n * 128u + ch0) = hv;
    } else {
        // fused head: per-lane partial logits over own 8 channels, shuffle-reduce
        float plg[NC];
        #pragma unroll
        for (int c = 0; c < NC; c++) {
            const f4* wr = (const f4*)(WoT + c * HIDU + ch0);
            f4 wa = wr[0], wb = wr[1];
            plg[c] = val0[0] * wa[0] + val0[1] * wa[1] + val0[2] * wa[2] + val0[3] * wa[3]
                   + val1[0] * wb[0] + val1[1] * wb[1] + val1[2] * wb[2] + val1[3] * wb[3];
        }
        #pragma unroll
        for (int mask = 1; mask < 16; mask <<= 1) {
            #pragma unroll
            for (int c = 0; c < NC; c++) plg[c] += __shfl_xor(plg[c], mask);
        }
        float lg[NC];
        float mx = -INFINITY;
        #pragma unroll
        for (int c = 0; c < NC; c++) { lg[c] = plg[c] + boS[c]; mx = fmaxf(mx, lg[c]); }
        float sum = 0.f;
        #pragma unroll
        for (int c = 0; c < NC; c++) sum += __expf(lg[c] - mx);
        float lse = mx + __logf(sum);
        if (l16 < NC) out_logits[(size_t)n * NC + l16] = lg[l16] - lse;
    }
}

// ---------------- launch ----------------
extern "C" void kernel_launch(void* const* d_in, const int* in_sizes, int n_in,
                              void* d_out, int out_size, void* d_ws, size_t ws_size,
                              hipStream_t stream) {
    const int*   ei    = (const int*)d_in[1];
    const float* eattr = (const float*)d_in[2];
    const float* x     = (const float*)d_in[0];
    const float *Wq0 = (const float*)d_in[3],  *bq0 = (const float*)d_in[4];
    const float *Wk0 = (const float*)d_in[5],  *bk0 = (const float*)d_in[6];
    const float *Wv0 = (const float*)d_in[7],  *bv0 = (const float*)d_in[8];
    const float *We0 = (const float*)d_in[9];
    const float *Ws0 = (const float*)d_in[10], *bs0 = (const float*)d_in[11];
    const float *Wq1 = (const float*)d_in[12], *bq1 = (const float*)d_in[13];
    const float *Wk1 = (const float*)d_in[14], *bk1 = (const float*)d_in[15];
    const float *Wv1 = (const float*)d_in[16], *bv1 = (const float*)d_in[17];
    const float *We1 = (const float*)d_in[18];
    const float *Ws1 = (const float*)d_in[19], *bs1 = (const float*)d_in[20];
    const float *Wout = (const float*)d_in[21], *bout = (const float*)d_in[22];

    char* p = (char*)d_ws;
    auto alloc = [&](size_t bytes) -> void* {
        void* r = (void*)p;
        p += (bytes + 255) & ~(size_t)255;
        return r;
    };
    int* deg      = (int*)alloc(NN * 4);
    int* row_ptr  = (int*)alloc((NN + 1) * 4);
    int* cursor   = (int*)alloc(NN * 4);
    int* bsum     = (int*)alloc(NBLK * 4);
    int* boff     = (int*)alloc(NBLK * 4);
    int* csr_src  = (int*)alloc((size_t)NE * 4);
    float* qb     = (float*)alloc((size_t)NN * HIDU * 4);
    u16* kb       = (u16*)alloc((size_t)NN * HIDU * 2);
    u16* vb       = (u16*)alloc((size_t)NN * HIDU * 2);
    float* sbuf   = (float*)alloc((size_t)NN * HIDU * 4);
    u16* hb16     = (u16*)alloc((size_t)NN * HIDU * 2);   // bf16 layer-1 output
    u16* ea16     = (u16*)alloc((size_t)NE * 16 * 2);     // CSR-ordered bf16 edge_attr
    u16* wthi     = (u16*)alloc(8 * 16384 * 2);

    // --- preprocessing: cooperative fused kernel if the runtime permits, else
    //     the R7-proven ordinary-kernel chain. Grid sized by occupancy QUERY
    //     (R9 lesson: never hard-code a cooperative grid; check the return code).
    static int g_prep_grid = -1;   // -1 = unqueried, 0 = coop disabled
    if (g_prep_grid < 0) {
        int maxb = 0;
        hipError_t qe = hipOccupancyMaxActiveBlocksPerMultiprocessor(&maxb, k_prep, 256, 0);
        if (qe != hipSuccess || maxb < 1) {
            g_prep_grid = NBLK;            // conservative, R8-proven size
        } else {
            long g = (long)maxb * 256;     // 256 CUs on MI355X
            if (g > PREPB_CAP) g = PREPB_CAP;
            if (g < NBLK) g = NBLK;
            g_prep_grid = (int)g;
        }
        (void)hipGetLastError();
    }

    bool coop_done = false;
    if (g_prep_grid > 0) {
        void* args[] = {
            (void*)&ei, (void*)&eattr,
            (void*)&Wq0, (void*)&Wk0, (void*)&Wv0, (void*)&Ws0,
            (void*)&Wq1, (void*)&Wk1, (void*)&Wv1, (void*)&Ws1,
            (void*)&deg, (void*)&bsum, (void*)&boff, (void*)&row_ptr,
            (void*)&cursor, (void*)&csr_src, (void*)&ea16, (void*)&wthi
        };
        hipError_t le = hipLaunchCooperativeKernel((void*)k_prep, dim3(g_prep_grid),
                                                   dim3(256), args, 0, stream);
        if (le == hipSuccess) {
            coop_done = true;
        } else {
            (void)hipGetLastError();       // clear sticky error
            g_prep_grid = 0;               // never try coop again this process
        }
    }
    if (!coop_done) {
        // fallback: ordinary-kernel prep chain (R7-proven)
        k_zcvt<<<512, 256, 0, stream>>>(Wq0, Wk0, Wv0, Ws0, Wq1, Wk1, Wv1, Ws1, deg, wthi);
        k_hist<<<(NE + 255) / 256, 256, 0, stream>>>(ei + NE, deg);
        scan_a<<<NBLK, 256, 0, stream>>>(deg, bsum);
        scan_b<<<1, 256, 0, stream>>>(bsum, boff, row_ptr);
        scan_c<<<NBLK, 256, 0, stream>>>(deg, boff, row_ptr, cursor);
        k_scatter<<<(NE + 255) / 256, 256, 0, stream>>>(ei, eattr, cursor, csr_src, ea16);
    }

    const int gm = (NN + 127) / 128;               // 391
    const int ga = (NN * 16) / 256;                // 3125 (exact)

    // layer 1 (single GEMM dispatch, 4 mats per block, X read once)
    gemm4<0><<<gm, 256, 0, stream>>>(x, wthi, bq0, bk0, bv0, bs0,
                                     qb, kb, vb, sbuf, NN);
    attn_t<0><<<ga, 256, 0, stream>>>(qb, kb, vb, sbuf, ea16, We0, row_ptr, csr_src,
                                      hb16, nullptr, nullptr, nullptr);
    // layer 2 (X = bf16 layer-1 output, loaded directly as A-fragments)
    gemm4<1><<<gm, 256, 0, stream>>>(hb16, wthi + 4 * 16384, bq1, bk1, bv1, bs1,
                                     qb, kb, vb, sbuf, NN);
    attn_t<1><<<ga, 256, 0, stream>>>(qb, kb, vb, sbuf, ea16, We1, row_ptr, csr_src,
                                      nullptr, Wout, bout, (float*)d_out);   // head fused
}

// Round 11
// 392.859 us; speedup vs baseline: 2.3460x; 2.3460x over previous
//
#include <hip/hip_runtime.h>

typedef unsigned short u16;
typedef unsigned int u32;
typedef __attribute__((ext_vector_type(4))) u16 u16x4;
typedef __attribute__((ext_vector_type(8))) u16 u16x8;
typedef __attribute__((ext_vector_type(4))) u32 u32x4;
typedef __attribute__((ext_vector_type(8))) short short8;   // MFMA A/B frag (8 bf16)
typedef __attribute__((ext_vector_type(4))) float f32x4;    // MFMA C/D frag
typedef __attribute__((ext_vector_type(4))) float f4;
typedef __attribute__((ext_vector_type(2))) float f2;

#define NN 50000
#define NE 600000
#define HEADS 4
#define DH 32
#define HIDU 128
#define NC 10
#define NBLK 196   // ceil(NN/256)
#define WES_T 34   // WeS t-stride (bank-spread)
#define WES_H 546  // WeS h-stride = 16*34 + 2

// logit scale folded with log2(e): (1/sqrt(32)) * 1.4426950408889634
#define SCALE2 0.25503486164f

__device__ __forceinline__ float bf2f(u16 u) {
    union { unsigned int i; float f; } c; c.i = ((unsigned int)u) << 16; return c.f;
}
__device__ __forceinline__ u16 f2bf(float f) {
    union { float f; unsigned int i; } c; c.f = f;
    unsigned int x = c.i;
    return (u16)((x + 0x7fffu + ((x >> 16) & 1u)) >> 16);  // RNE
}
__device__ __forceinline__ float lo_bf(u32 d) { return __uint_as_float(d << 16); }
__device__ __forceinline__ float hi_bf(u32 d) { return __uint_as_float(d & 0xffff0000u); }
// quad butterflies via DPP (VALU-only)
__device__ __forceinline__ float qadd_xor1(float v) {
    int o = __builtin_amdgcn_update_dpp(0, __float_as_int(v), 0xB1, 0xF, 0xF, true);
    return v + __int_as_float(o);
}
__device__ __forceinline__ float qadd_xor2(float v) {
    int o = __builtin_amdgcn_update_dpp(0, __float_as_int(v), 0x4E, 0xF, 0xF, true);
    return v + __int_as_float(o);
}

// ---------------- preprocessing (5 ordinary dispatches; no grid.sync — R10 lesson) ----

// zero deg + weight convert/transpose W[k][n] -> Wt[n][k] bf16 (grid-stride)
__global__ void k_zcvt(const float* w0, const float* w1, const float* w2, const float* w3,
                       const float* w4, const float* w5, const float* w6, const float* w7,
                       int* __restrict__ deg, u16* __restrict__ wthi) {
    int gid = blockIdx.x * 256 + threadIdx.x;
    int gsz = gridDim.x * 256;
    for (int i = gid; i < NN; i += gsz) deg[i] = 0;
    for (int idx = gid; idx < 8 * 16384; idx += gsz) {
        int mat = idx >> 14;
        int r   = idx & 16383;          // k*128 + n
        int k = r >> 7, n = r & 127;
        const float* w;
        switch (mat) {
            case 0: w = w0; break; case 1: w = w1; break;
            case 2: w = w2; break; case 3: w = w3; break;
            case 4: w = w4; break; case 5: w = w5; break;
            case 6: w = w6; break; default: w = w7; break;
        }
        wthi[mat * 16384 + n * 128 + k] = f2bf(w[r]);
    }
}

__global__ void k_hist(const int* __restrict__ dst, int* __restrict__ deg) {
    int i = blockIdx.x * blockDim.x + threadIdx.x;
    if (i < NE) atomicAdd(&deg[dst[i]], 1);
}

__global__ __launch_bounds__(256) void scan_a(const int* __restrict__ deg,
                                              int* __restrict__ bsum) {
    __shared__ int red[4];
    int i = blockIdx.x * 256 + threadIdx.x;
    int v = (i < NN) ? deg[i] : 0;
    #pragma unroll
    for (int off = 1; off < 64; off <<= 1) v += __shfl_xor(v, off);
    if ((threadIdx.x & 63) == 0) red[threadIdx.x >> 6] = v;
    __syncthreads();
    if (threadIdx.x == 0) bsum[blockIdx.x] = red[0] + red[1] + red[2] + red[3];
}

// fused scan_b+scan_c: each block derives its own exclusive block offset from bsum
// (NBLK=196 <= 256: one masked block-reduce), then scans its deg chunk.
__global__ __launch_bounds__(256) void scan_bc(const int* __restrict__ deg,
                                               const int* __restrict__ bsum,
                                               int* __restrict__ row_ptr,
                                               int* __restrict__ cursor) {
    __shared__ int s[256];
    __shared__ int red[4];
    const int t = threadIdx.x;
    // block offset = sum of bsum[i] for i < blockIdx.x
    int v = (t < blockIdx.x) ? bsum[t] : 0;   // blockIdx.x <= NBLK <= 256
    #pragma unroll
    for (int off = 1; off < 64; off <<= 1) v += __shfl_xor(v, off);
    if ((t & 63) == 0) red[t >> 6] = v;
    __syncthreads();
    const int boffv = red[0] + red[1] + red[2] + red[3];
    __syncthreads();
    // per-block inclusive scan of deg chunk (R7-proven body)
    int i = blockIdx.x * 256 + t;
    int dv = (i < NN) ? deg[i] : 0;
    s[t] = dv;
    __syncthreads();
    for (int off = 1; off < 256; off <<= 1) {
        int x = (t >= off) ? s[t - off] : 0;
        __syncthreads();
        s[t] += x;
        __syncthreads();
    }
    if (i < NN) {
        int r = boffv + s[t] - dv;
        row_ptr[i] = r;
        cursor[i] = r;
    }
    if (blockIdx.x == 0 && t == 0) row_ptr[NN] = NE;
}

// scatter: build csr_src AND permute edge_attr into CSR order (fp32 -> bf16)
__global__ void k_scatter(const int* __restrict__ ei, const float* __restrict__ eattr,
                          int* __restrict__ cursor,
                          int* __restrict__ csr_src, u16* __restrict__ ea16) {
    int i = blockIdx.x * blockDim.x + threadIdx.x;
    if (i < NE) {
        int sN = ei[i];
        int d = ei[NE + i];
        int pos = atomicAdd(&cursor[d], 1);
        csr_src[pos] = sN;
        const f4* ep = (const f4*)(eattr + (size_t)i * 16);
        f4 a = ep[0], b = ep[1], c = ep[2], dd = ep[3];
        u16x8 o0, o1;
        #pragma unroll
        for (int j = 0; j < 4; j++) {
            o0[j] = f2bf(a[j]); o0[4 + j] = f2bf(b[j]);
            o1[j] = f2bf(c[j]); o1[4 + j] = f2bf(dd[j]);
        }
        *(u16x8*)(ea16 + (size_t)pos * 16)     = o0;
        *(u16x8*)(ea16 + (size_t)pos * 16 + 8) = o1;
    }
}

// ---------------- unified q/k/v/s GEMM: 4 mats per block, X read ONCE -----------
// grid (391). A-fragments (K=128) live in registers; loop mats {reload Bs, MFMA, write}.
// q,s -> fp32; k,v -> bf16. XB=0: X fp32 (trunc); XB=1: X bf16.
template<int XB>
__global__ __launch_bounds__(256) void gemm4(
    const void* __restrict__ Xv, const u16* __restrict__ WtHi,
    const float* __restrict__ b0, const float* __restrict__ b1,
    const float* __restrict__ b2, const float* __restrict__ b3,
    float* __restrict__ outq, u16* __restrict__ outk, u16* __restrict__ outv,
    float* __restrict__ outs, int nrows)
{
    __shared__ u16 Bs[128 * 128];   // 32 KB
    const float* Xf = (const float*)Xv;
    const u16*   Xh = (const u16*)Xv;

    const int wave = threadIdx.x >> 6, lane = threadIdx.x & 63;
    const int n0 = lane & 15;
    const int qw = lane >> 4;
    const int kq = qw * 8;

    // ---- load A-fragments ONCE (per lane: 2 row-tiles x 4 k-slices x 8 bf16 = 32 VGPR)
    short8 ah[2][4];
    #pragma unroll
    for (int rt = 0; rt < 2; rt++) {
        int arow = blockIdx.x * 128 + wave * 32 + rt * 16 + n0;
        int arow_c = arow < nrows ? arow : nrows - 1;
        size_t xbase = (size_t)arow_c * HIDU + kq;
        #pragma unroll
        for (int ks = 0; ks < 4; ks++) {
            if (XB) {
                ah[rt][ks] = *(const short8*)(Xh + xbase + ks * 32);
            } else {
                f4 a0 = *(const f4*)(Xf + xbase + ks * 32);
                f4 a1 = *(const f4*)(Xf + xbase + ks * 32 + 4);
                #pragma unroll
                for (int j = 0; j < 4; j++) {
                    ah[rt][ks][j]     = (short)(__float_as_uint(a0[j]) >> 16);
                    ah[rt][ks][4 + j] = (short)(__float_as_uint(a1[j]) >> 16);
                }
            }
        }
    }

    #pragma unroll
    for (int mat = 0; mat < 4; mat++) {
        if (mat > 0) __syncthreads();   // all waves done reading previous Bs
        const u16* wh = WtHi + mat * 16384;
        #pragma unroll
        for (int i = 0; i < 8; i++) {
            int idx = threadIdx.x + i * 256;
            int n = idx >> 4, g = idx & 15;
            *(u16x8*)(&Bs[n * 128 + ((g ^ (n & 15)) << 3)]) = *(const u16x8*)(wh + n * 128 + g * 8);
        }
        __syncthreads();

        f32x4 acc[2][8];
        #pragma unroll
        for (int rt = 0; rt < 2; rt++)
            #pragma unroll
            for (int nt = 0; nt < 8; nt++) acc[rt][nt] = (f32x4){0.f, 0.f, 0.f, 0.f};

        #pragma unroll
        for (int ks = 0; ks < 4; ks++) {
            #pragma unroll
            for (int nt = 0; nt < 8; nt++) {
                const int boff = (nt * 16 + n0) * 128 + (((ks << 2) + qw) ^ n0) * 8;
                short8 bh = *(const short8*)(&Bs[boff]);
                #pragma unroll
                for (int rt = 0; rt < 2; rt++)
                    acc[rt][nt] = __builtin_amdgcn_mfma_f32_16x16x32_bf16(ah[rt][ks], bh, acc[rt][nt], 0, 0, 0);
            }
        }

        const float* bia = (mat == 0) ? b0 : (mat == 1) ? b1 : (mat == 2) ? b2 : b3;
        #pragma unroll
        for (int rt = 0; rt < 2; rt++) {
            const int rbase = blockIdx.x * 128 + wave * 32 + rt * 16 + qw * 4;
            #pragma unroll
            for (int nt = 0; nt < 8; nt++) {
                int col = nt * 16 + n0;
                float bv = bia[col];
                #pragma unroll
                for (int r = 0; r < 4; r++) {
                    int grow = rbase + r;
                    if (grow < nrows) {
                        float v = acc[rt][nt][r] + bv;
                        if (mat == 0)      outq[(size_t)grow * HIDU + col] = v;
                        else if (mat == 1) outk[(size_t)grow * HIDU + col] = f2bf(v);
                        else if (mat == 2) outv[(size_t)grow * HIDU + col] = f2bf(v);
                        else               outs[(size_t)grow * HIDU + col] = v;
                    }
                }
            }
        }
    }
}

// ---------------- fused attention (+ optional fused head) ----------------
// 16 lanes per node (4 heads x 4 subs); DPP quad butterflies; f4 packed math.
// Max-free single-pass softmax (verified R2-R8). 32-bit gather offsets.
// MODE 0: write relu(conv_out) rows bf16. MODE 1: fused output head + log_softmax.
template<int MODE>
__global__ __launch_bounds__(256) void attn_t(
    const float* __restrict__ qb, const u16* __restrict__ kb, const u16* __restrict__ vb,
    const float* __restrict__ sb, const u16* __restrict__ ea16, const float* __restrict__ We,
    const int* __restrict__ row_ptr, const int* __restrict__ csr_src,
    u16* __restrict__ hout_b16,
    const float* __restrict__ Wout, const float* __restrict__ bout,
    float* __restrict__ out_logits)
{
    __shared__ float WeS[4 * WES_H];    // ~8.7 KB
    __shared__ float WoT[MODE ? (NC * HIDU) : 1];  // transposed head weights (mode 1)
    __shared__ float boS[MODE ? NC : 1];

    #pragma unroll
    for (int i = 0; i < 8; i++) {
        int idx = threadIdx.x + i * 256;   // t*128 + c over 16x128
        int tt = idx >> 7, c = idx & 127;
        int h = c >> 5, j = c & 31;
        WeS[h * WES_H + tt * WES_T + j] = We[idx];
    }
    if (MODE == 1) {
        #pragma unroll
        for (int i = 0; i < 5; i++) {
            int idx = threadIdx.x + i * 256;
            if (idx < HIDU * NC) {
                int c = idx >> 7, ch = idx & 127;       // WoT[c][ch] = Wout[ch][c]
                WoT[idx] = Wout[ch * NC + c];
            }
        }
        if (threadIdx.x < NC) boS[threadIdx.x] = bout[threadIdx.x];
    }
    __syncthreads();

    int gtid = blockIdx.x * 256 + threadIdx.x;   // grid is exactly NN*16 threads
    int n   = gtid >> 4;
    int l16 = gtid & 15;
    int h   = l16 >> 2;
    int sub = l16 & 3;
    const int lane = threadIdx.x & 63;
    const float* WeH = &WeS[h * WES_H];
    const int j0  = sub * 8;
    const int ch0 = h * DH + j0;   // = l16*8
    const int t0  = sub * 4;

    // own 8 q channels (coalesced: 16 lanes cover the full 128-f32 row)
    f4 qa, qbv;
    {
        const f4* qp = (const f4*)(qb + (size_t)n * HIDU + ch0);
        qa = qp[0]; qbv = qp[1];
    }

    // g[t] = q_head . We[t, head]: partial over own 8 channels for all 16 t,
    // then quad butterfly-reduce across the 4 sub-lanes.
    f4 g4v;
    {
        float part[16];
        #pragma unroll
        for (int t = 0; t < 16; t++) {
            const f2* wp = (const f2*)(WeH + t * WES_T + j0);
            f2 w0 = wp[0], w1 = wp[1], w2 = wp[2], w3 = wp[3];
            part[t] = qa[0] * w0.x + qa[1] * w0.y + qa[2] * w1.x + qa[3] * w1.y
                    + qbv[0] * w2.x + qbv[1] * w2.y + qbv[2] * w3.x + qbv[3] * w3.y;
        }
        #pragma unroll
        for (int t = 0; t < 16; t++) { part[t] = qadd_xor1(part[t]); part[t] = qadd_xor2(part[t]); }
        g4v[0] = part[t0]; g4v[1] = part[t0 + 1]; g4v[2] = part[t0 + 2]; g4v[3] = part[t0 + 3];
    }

    float l = 0.f;
    f4 O0 = {0.f, 0.f, 0.f, 0.f}, O1 = {0.f, 0.f, 0.f, 0.f};
    f4 a4 = {0.f, 0.f, 0.f, 0.f};

    const int r0 = row_ptr[n], r1 = row_ptr[n + 1];

    for (int e = r0; e < r1; e += 4) {
        const int e1 = (e + 1 < r1) ? e + 1 : e;
        const int e2 = (e + 2 < r1) ? e + 2 : e;
        const int e3 = (e + 3 < r1) ? e + 3 : e;
        // issue ALL loads up-front (MLP); all offsets 32-bit (buffers < 20 MB)
        int s0 = csr_src[e], s1 = csr_src[e1], s2 = csr_src[e2], s3 = csr_src[e3];
        u32 eo0 = (u32)e  * 16u + t0, eo1 = (u32)e1 * 16u + t0;
        u32 eo2 = (u32)e2 * 16u + t0, eo3 = (u32)e3 * 16u + t0;
        u16x4 x0 = *(const u16x4*)(ea16 + eo0);
        u16x4 x1 = *(const u16x4*)(ea16 + eo1);
        u16x4 x2 = *(const u16x4*)(ea16 + eo2);
        u16x4 x3 = *(const u16x4*)(ea16 + eo3);
        u32 ko0 = (u32)s0 * 128u + ch0, ko1 = (u32)s1 * 128u + ch0;
        u32 ko2 = (u32)s2 * 128u + ch0, ko3 = (u32)s3 * 128u + ch0;
        u32x4 k0 = *(const u32x4*)(kb + ko0);
        u32x4 k1 = *(const u32x4*)(kb + ko1);
        u32x4 k2 = *(const u32x4*)(kb + ko2);
        u32x4 k3 = *(const u32x4*)(kb + ko3);
        u32x4 v0 = *(const u32x4*)(vb + ko0);
        u32x4 v1 = *(const u32x4*)(vb + ko1);
        u32x4 v2 = *(const u32x4*)(vb + ko2);
        u32x4 v3 = *(const u32x4*)(vb + ko3);

        f4 ea0 = {bf2f(x0[0]), bf2f(x0[1]), bf2f(x0[2]), bf2f(x0[3])};
        f4 ea1 = {bf2f(x1[0]), bf2f(x1[1]), bf2f(x1[2]), bf2f(x1[3])};
        f4 ea2 = {bf2f(x2[0]), bf2f(x2[1]), bf2f(x2[2]), bf2f(x2[3])};
        f4 ea3 = {bf2f(x3[0]), bf2f(x3[1]), bf2f(x3[2]), bf2f(x3[3])};

        f4 ac0 = qa * (f4){lo_bf(k0[0]), hi_bf(k0[0]), lo_bf(k0[1]), hi_bf(k0[1])}
               + qbv * (f4){lo_bf(k0[2]), hi_bf(k0[2]), lo_bf(k0[3]), hi_bf(k0[3])}
               + g4v * ea0;
        f4 ac1 = qa * (f4){lo_bf(k1[0]), hi_bf(k1[0]), lo_bf(k1[1]), hi_bf(k1[1])}
               + qbv * (f4){lo_bf(k1[2]), hi_bf(k1[2]), lo_bf(k1[3]), hi_bf(k1[3])}
               + g4v * ea1;
        f4 ac2 = qa * (f4){lo_bf(k2[0]), hi_bf(k2[0]), lo_bf(k2[1]), hi_bf(k2[1])}
               + qbv * (f4){lo_bf(k2[2]), hi_bf(k2[2]), lo_bf(k2[3]), hi_bf(k2[3])}
               + g4v * ea2;
        f4 ac3 = qa * (f4){lo_bf(k3[0]), hi_bf(k3[0]), lo_bf(k3[1]), hi_bf(k3[1])}
               + qbv * (f4){lo_bf(k3[2]), hi_bf(k3[2]), lo_bf(k3[3]), hi_bf(k3[3])}
               + g4v * ea3;
        float d0 = (ac0[0] + ac0[1]) + (ac0[2] + ac0[3]);
        float d1 = (ac1[0] + ac1[1]) + (ac1[2] + ac1[3]);
        float d2 = (ac2[0] + ac2[1]) + (ac2[2] + ac2[3]);
        float d3 = (ac3[0] + ac3[1]) + (ac3[2] + ac3[3]);
        d0 = qadd_xor1(d0); d1 = qadd_xor1(d1); d2 = qadd_xor1(d2); d3 = qadd_xor1(d3);
        d0 = qadd_xor2(d0); d1 = qadd_xor2(d1); d2 = qadd_xor2(d2); d3 = qadd_xor2(d3);

        // max-free softmax weights (logits provably small for this model; verified R2-R8)
        float w0 = exp2f(d0 * SCALE2);
        float w1 = (e + 1 < r1) ? exp2f(d1 * SCALE2) : 0.f;
        float w2 = (e + 2 < r1) ? exp2f(d2 * SCALE2) : 0.f;
        float w3 = (e + 3 < r1) ? exp2f(d3 * SCALE2) : 0.f;
        l += (w0 + w1) + (w2 + w3);

        O0 = O0
           + (f4){lo_bf(v0[0]), hi_bf(v0[0]), lo_bf(v0[1]), hi_bf(v0[1])} * w0
           + (f4){lo_bf(v1[0]), hi_bf(v1[0]), lo_bf(v1[1]), hi_bf(v1[1])} * w1
           + (f4){lo_bf(v2[0]), hi_bf(v2[0]), lo_bf(v2[1]), hi_bf(v2[1])} * w2
           + (f4){lo_bf(v3[0]), hi_bf(v3[0]), lo_bf(v3[1]), hi_bf(v3[1])} * w3;
        O1 = O1
           + (f4){lo_bf(v0[2]), hi_bf(v0[2]), lo_bf(v0[3]), hi_bf(v0[3])} * w0
           + (f4){lo_bf(v1[2]), hi_bf(v1[2]), lo_bf(v1[3]), hi_bf(v1[3])} * w1
           + (f4){lo_bf(v2[2]), hi_bf(v2[2]), lo_bf(v2[3]), hi_bf(v2[3])} * w2
           + (f4){lo_bf(v3[2]), hi_bf(v3[2]), lo_bf(v3[3]), hi_bf(v3[3])} * w3;
        a4 = a4 + ea0 * w0 + ea1 * w1 + ea2 * w2 + ea3 * w3;
    }

    // gather distributed a16 (from the 4 lanes of this head)
    float af[16];
    #pragma unroll
    for (int t = 0; t < 16; t++)
        af[t] = __shfl(a4[t & 3], (lane & ~3) | (t >> 2));

    float invl = 1.0f / (l + 1e-16f);     // PyG softmax eps; zero-degree -> O=0
    const f4* sp = (const f4*)(sb + (size_t)n * HIDU + ch0);
    f4 sp0 = sp[0], sp1 = sp[1];

    // ev_j = sum_t af[t] * WeH[t][j0+j]  (vectorized b64 LDS reads)
    f4 evA = {0.f, 0.f, 0.f, 0.f}, evB = {0.f, 0.f, 0.f, 0.f};
    #pragma unroll
    for (int t = 0; t < 16; t++) {
        float a = af[t];
        const f2* wp = (const f2*)(WeH + t * WES_T + j0);
        f2 w0 = wp[0], w1 = wp[1], w2 = wp[2], w3 = wp[3];
        evA[0] += a * w0.x; evA[1] += a * w0.y; evA[2] += a * w1.x; evA[3] += a * w1.y;
        evB[0] += a * w2.x; evB[1] += a * w2.y; evB[2] += a * w3.x; evB[3] += a * w3.y;
    }

    f4 val0, val1;
    #pragma unroll
    for (int j = 0; j < 4; j++) {
        val0[j] = fmaxf((O0[j] + evA[j]) * invl + sp0[j], 0.f);
        val1[j] = fmaxf((O1[j] + evB[j]) * invl + sp1[j], 0.f);
    }

    if (MODE == 0) {
        u16x8 hv;
        #pragma unroll
        for (int j = 0; j < 4; j++) { hv[j] = f2bf(val0[j]); hv[4 + j] = f2bf(val1[j]); }
        *(u16x8*)(hout_b16 + (u32)n * 128u + ch0) = hv;
    } else {
        // fused head: per-lane partial logits over own 8 channels, shuffle-reduce
        float plg[NC];
        #pragma unroll
        for (int c = 0; c < NC; c++) {
            const f4* wr = (const f4*)(WoT + c * HIDU + ch0);
            f4 wa = wr[0], wb = wr[1];
            plg[c] = val0[0] * wa[0] + val0[1] * wa[1] + val0[2] * wa[2] + val0[3] * wa[3]
                   + val1[0] * wb[0] + val1[1] * wb[1] + val1[2] * wb[2] + val1[3] * wb[3];
        }
        #pragma unroll
        for (int mask = 1; mask < 16; mask <<= 1) {
            #pragma unroll
            for (int c = 0; c < NC; c++) plg[c] += __shfl_xor(plg[c], mask);
        }
        float lg[NC];
        float mx = -INFINITY;
        #pragma unroll
        for (int c = 0; c < NC; c++) { lg[c] = plg[c] + boS[c]; mx = fmaxf(mx, lg[c]); }
        float sum = 0.f;
        #pragma unroll
        for (int c = 0; c < NC; c++) sum += __expf(lg[c] - mx);
        float lse = mx + __logf(sum);
        if (l16 < NC) out_logits[(size_t)n * NC + l16] = lg[l16] - lse;
    }
}

// ---------------- launch ----------------
extern "C" void kernel_launch(void* const* d_in, const int* in_sizes, int n_in,
                              void* d_out, int out_size, void* d_ws, size_t ws_size,
                              hipStream_t stream) {
    const float* x     = (const float*)d_in[0];
    const int*   ei    = (const int*)d_in[1];
    const float* eattr = (const float*)d_in[2];
    const float *Wq0 = (const float*)d_in[3],  *bq0 = (const float*)d_in[4];
    const float *Wk0 = (const float*)d_in[5],  *bk0 = (const float*)d_in[6];
    const float *Wv0 = (const float*)d_in[7],  *bv0 = (const float*)d_in[8];
    const float *We0 = (const float*)d_in[9];
    const float *Ws0 = (const float*)d_in[10], *bs0 = (const float*)d_in[11];
    const float *Wq1 = (const float*)d_in[12], *bq1 = (const float*)d_in[13];
    const float *Wk1 = (const float*)d_in[14], *bk1 = (const float*)d_in[15];
    const float *Wv1 = (const float*)d_in[16], *bv1 = (const float*)d_in[17];
    const float *We1 = (const float*)d_in[18];
    const float *Ws1 = (const float*)d_in[19], *bs1 = (const float*)d_in[20];
    const float *Wout = (const float*)d_in[21], *bout = (const float*)d_in[22];

    char* p = (char*)d_ws;
    auto alloc = [&](size_t bytes) -> void* {
        void* r = (void*)p;
        p += (bytes + 255) & ~(size_t)255;
        return r;
    };
    int* deg      = (int*)alloc(NN * 4);
    int* row_ptr  = (int*)alloc((NN + 1) * 4);
    int* cursor   = (int*)alloc(NN * 4);
    int* bsum     = (int*)alloc(NBLK * 4);
    int* csr_src  = (int*)alloc((size_t)NE * 4);
    float* qb     = (float*)alloc((size_t)NN * HIDU * 4);
    u16* kb       = (u16*)alloc((size_t)NN * HIDU * 2);
    u16* vb       = (u16*)alloc((size_t)NN * HIDU * 2);
    float* sbuf   = (float*)alloc((size_t)NN * HIDU * 4);
    u16* hb16     = (u16*)alloc((size_t)NN * HIDU * 2);   // bf16 layer-1 output
    u16* ea16     = (u16*)alloc((size_t)NE * 16 * 2);     // CSR-ordered bf16 edge_attr
    u16* wthi     = (u16*)alloc(8 * 16384 * 2);

    // preprocessing: 5 ordinary dispatches (coop grid.sync rejected — R8/R10 evidence)
    k_zcvt<<<512, 256, 0, stream>>>(Wq0, Wk0, Wv0, Ws0, Wq1, Wk1, Wv1, Ws1, deg, wthi);
    k_hist<<<(NE + 255) / 256, 256, 0, stream>>>(ei + NE, deg);
    scan_a<<<NBLK, 256, 0, stream>>>(deg, bsum);
    scan_bc<<<NBLK, 256, 0, stream>>>(deg, bsum, row_ptr, cursor);
    k_scatter<<<(NE + 255) / 256, 256, 0, stream>>>(ei, eattr, cursor, csr_src, ea16);

    const int gm = (NN + 127) / 128;               // 391
    const int ga = (NN * 16) / 256;                // 3125 (exact)

    // layer 1 (single GEMM dispatch, 4 mats per block, X read once)
    gemm4<0><<<gm, 256, 0, stream>>>(x, wthi, bq0, bk0, bv0, bs0,
                                     qb, kb, vb, sbuf, NN);
    attn_t<0><<<ga, 256, 0, stream>>>(qb, kb, vb, sbuf, ea16, We0, row_ptr, csr_src,
                                      hb16, nullptr, nullptr, nullptr);
    // layer 2 (X = bf16 layer-1 output, loaded directly as A-fragments)
    gemm4<1><<<gm, 256, 0, stream>>>(hb16, wthi + 4 * 16384, bq1, bk1, bv1, bs1,
                                     qb, kb, vb, sbuf, NN);
    attn_t<1><<<ga, 256, 0, stream>>>(qb, kb, vb, sbuf, ea16, We1, row_ptr, csr_src,
                                      nullptr, Wout, bout, (float*)d_out);   // head fused
}